// Round 5
// baseline (251.789 us; speedup 1.0000x reference)
//
#include <hip/hip_runtime.h>
#include <stdint.h>
#include <stddef.h>

#define H 512
#define XD 256
#define NCHLD 32768
#define BM 128              // rows per block (4 M-tiles)
#define BN 128              // children per block (256 N-tiles)
#define KTP 64              // K per phase
#define NPH 8               // phases
#define BP 68               // Bs pitch in f16 (136 B) -> conflict-free b128
#define NSHARD 32

// ws layout (floats):
#define WS_PREF 0           // [0,512)      pre_f = w_f@x + b_f
#define WS_IOU  512         // [512,2048)   iou logits
#define WS_CACC 2048        // [2048,18432)  32 shards x 512
#define WS_HSUM 18432       // [18432,34816) 32 shards x 512
#define WS_UF16 34816       // u_f as f16: 262144 halves = 131072 float slots

typedef float f32x4 __attribute__((ext_vector_type(4)));
typedef _Float16 f16x8 __attribute__((ext_vector_type(8)));
typedef _Float16 f16x4 __attribute__((ext_vector_type(4)));

__device__ __forceinline__ float sigm(float x) { return 1.0f / (1.0f + __expf(-x)); }

__device__ __forceinline__ void gload_lds16(const _Float16* g, void* l) {
    __builtin_amdgcn_global_load_lds((const __attribute__((address_space(1))) void*)g,
                                     (__attribute__((address_space(3))) void*)l,
                                     16, 0, 0);
}

// k0: (a) u_f -> f16 (blocks 0..255); (b) pre_f + zero shard arrays (blocks 256..263).
__global__ __launch_bounds__(256) void k0_setup(const float* __restrict__ x,
                                                const float* __restrict__ w_f,
                                                const float* __restrict__ b_f,
                                                const float* __restrict__ u_f,
                                                float* __restrict__ ws) {
    const int b = blockIdx.x;
    if (b < 256) {
        const int i = (b * 256 + threadIdx.x) * 4;
        float4 v = *(const float4*)(u_f + i);
        f16x4 h;
        h[0] = (_Float16)v.x; h[1] = (_Float16)v.y;
        h[2] = (_Float16)v.z; h[3] = (_Float16)v.w;
        *(f16x4*)((_Float16*)(ws + WS_UF16) + i) = h;
    } else {
        const int gid = (b - 256) * 256 + threadIdx.x;   // [0,2048)
        const int row = gid >> 2;
        const int part = gid & 3;
        const float4* wr = (const float4*)(w_f + (size_t)row * XD) + part * 16;
        const float4* xv = (const float4*)x + part * 16;
        float acc = 0.0f;
#pragma unroll 4
        for (int i = 0; i < 16; ++i) {
            float4 a = wr[i], c = xv[i];
            acc += a.x * c.x + a.y * c.y + a.z * c.z + a.w * c.w;
        }
        acc += __shfl_xor(acc, 1);
        acc += __shfl_xor(acc, 2);
        if (part == 0) ws[WS_PREF + row] = acc + b_f[row];
        // zero CACC+HSUM = floats [2048, 34816) = float4 idx [512, 8704)
        float4 z = make_float4(0.f, 0.f, 0.f, 0.f);
#pragma unroll
        for (int t = 0; t < 4; ++t)
            ((float4*)ws)[512 + gid * 4 + t] = z;
    }
}

// k2: two-tile MFMA GEMM. A (u_f16) DMA'd to LDS (swizzled), B (hs) cvt-staged to LDS,
// 8 dbuf phases, 1 barrier/phase. Fused: h_sum (mtile==0), sigmoid+cs epilogue.
__global__ __launch_bounds__(512, 4) void k2_main(const float* __restrict__ hs,
                                                  const float* __restrict__ cs,
                                                  float* __restrict__ ws) {
    __shared__ _Float16 As[2][BM * 64];   // 32 KB, linear (DMA dest), seg-swizzled
    __shared__ _Float16 Bs[2][BN][BP];    // 34.8 KB
    __shared__ float hsum_l[H];           // 2 KB

    const _Float16* uf16 = (const _Float16*)(ws + WS_UF16);
    const float* pre_f = ws + WS_PREF;
    const int bid   = blockIdx.x;
    const int ntile = bid >> 2;
    const int mtile = bid & 3;
    const int c0    = ntile * BN;
    const int r0    = mtile * BM;

    const int tid  = threadIdx.x;
    const int wid  = tid >> 6;
    const int lane = tid & 63;

    // B staging map: thread -> (child ch, k-quarter kq)
    const int ch = tid >> 2;
    const int kq = tid & 3;
    const float4* bsrc = (const float4*)(hs + (size_t)(c0 + ch) * H) + kq * 4;

    // A DMA: wave covers segs [wid*128, wid*128+128) in 2 issues of 64
    const int dd0  = wid * 128 + lane;        // i=0 seg index for this lane
    const int row0 = dd0 >> 3;
    const int sl0  = (dd0 & 7) ^ (row0 & 7);
    const _Float16* asrc0 = uf16 + (size_t)(r0 + row0) * H + sl0 * 8;
    const int dd1  = dd0 + 64;
    const int row1 = dd1 >> 3;
    const int sl1  = (dd1 & 7) ^ (row1 & 7);
    const _Float16* asrc1 = uf16 + (size_t)(r0 + row1) * H + sl1 * 8;

    // wave tiling: wm in [0,4) owns rows wm*32..+32 (2 rt), wn in [0,2) owns ch wn*64..+64 (4 ct)
    const int wm = wid >> 1;
    const int wn = wid & 1;
    const int fc = lane & 15;    // fragment row/col
    const int q  = lane >> 4;

#define ISSUE_A(p, buf)                                                          \
    {                                                                            \
        gload_lds16(asrc0 + (p) * KTP, (char*)&As[buf][0] + (wid * 128) * 16);   \
        gload_lds16(asrc1 + (p) * KTP, (char*)&As[buf][0] + (wid * 128 + 64) * 16); \
    }

#define WRITE_B(p, buf, b0, b1, b2, b3)                                          \
    {                                                                            \
        _Float16* bd = &Bs[buf][ch][kq * 16];                                    \
        f16x8 lo, hi;                                                            \
        lo[0] = (_Float16)(b0).x; lo[1] = (_Float16)(b0).y;                      \
        lo[2] = (_Float16)(b0).z; lo[3] = (_Float16)(b0).w;                      \
        lo[4] = (_Float16)(b1).x; lo[5] = (_Float16)(b1).y;                      \
        lo[6] = (_Float16)(b1).z; lo[7] = (_Float16)(b1).w;                      \
        hi[0] = (_Float16)(b2).x; hi[1] = (_Float16)(b2).y;                      \
        hi[2] = (_Float16)(b2).z; hi[3] = (_Float16)(b2).w;                      \
        hi[4] = (_Float16)(b3).x; hi[5] = (_Float16)(b3).y;                      \
        hi[6] = (_Float16)(b3).z; hi[7] = (_Float16)(b3).w;                      \
        *(f16x8*)bd = lo;                                                        \
        *(f16x8*)(bd + 8) = hi;                                                  \
        if (mtile == 0) {                                                        \
            float4 v0 = b0, v1 = b1, v2 = b2, v3 = b3;                           \
            _Pragma("unroll")                                                    \
            for (int m = 4; m <= 32; m <<= 1) {                                  \
                v0.x += __shfl_xor(v0.x, m); v0.y += __shfl_xor(v0.y, m);        \
                v0.z += __shfl_xor(v0.z, m); v0.w += __shfl_xor(v0.w, m);        \
                v1.x += __shfl_xor(v1.x, m); v1.y += __shfl_xor(v1.y, m);        \
                v1.z += __shfl_xor(v1.z, m); v1.w += __shfl_xor(v1.w, m);        \
                v2.x += __shfl_xor(v2.x, m); v2.y += __shfl_xor(v2.y, m);        \
                v2.z += __shfl_xor(v2.z, m); v2.w += __shfl_xor(v2.w, m);        \
                v3.x += __shfl_xor(v3.x, m); v3.y += __shfl_xor(v3.y, m);        \
                v3.z += __shfl_xor(v3.z, m); v3.w += __shfl_xor(v3.w, m);        \
            }                                                                    \
            if (lane < 4) {                                                      \
                float* hd = &hsum_l[(p) * KTP + lane * 16];                      \
                atomicAdd(hd + 0,  v0.x); atomicAdd(hd + 1,  v0.y);              \
                atomicAdd(hd + 2,  v0.z); atomicAdd(hd + 3,  v0.w);              \
                atomicAdd(hd + 4,  v1.x); atomicAdd(hd + 5,  v1.y);              \
                atomicAdd(hd + 6,  v1.z); atomicAdd(hd + 7,  v1.w);              \
                atomicAdd(hd + 8,  v2.x); atomicAdd(hd + 9,  v2.y);              \
                atomicAdd(hd + 10, v2.z); atomicAdd(hd + 11, v2.w);              \
                atomicAdd(hd + 12, v3.x); atomicAdd(hd + 13, v3.y);              \
                atomicAdd(hd + 14, v3.z); atomicAdd(hd + 15, v3.w);              \
            }                                                                    \
        }                                                                        \
    }

    // ---- prologue: phase 0 ----
    ISSUE_A(0, 0)
    float4 b0 = bsrc[0], b1 = bsrc[1], b2 = bsrc[2], b3 = bsrc[3];
    if (tid < H) hsum_l[tid] = 0.0f;
    __syncthreads();            // zeros visible; A0 DMA drained
    WRITE_B(0, 0, b0, b1, b2, b3)
    __syncthreads();            // B0 visible

    f32x4 acc[2][4];
    const f32x4 vzero = {0.0f, 0.0f, 0.0f, 0.0f};
#pragma unroll
    for (int rt = 0; rt < 2; ++rt)
#pragma unroll
        for (int ct = 0; ct < 4; ++ct)
            acc[rt][ct] = vzero;

    // ---- main phases ----
    int cur = 0;
#pragma unroll
    for (int p = 0; p < NPH; ++p) {
        float4 n0, n1, n2, n3;
        if (p + 1 < NPH) {
            ISSUE_A(p + 1, cur ^ 1)
            const float4* bs = bsrc + (p + 1) * 16;
            n0 = bs[0]; n1 = bs[1]; n2 = bs[2]; n3 = bs[3];
        }

        // compute on buffer `cur`
#pragma unroll
        for (int kk = 0; kk < 2; ++kk) {
            f16x8 af[2];
#pragma unroll
            for (int rt = 0; rt < 2; ++rt) {
                const int ar  = wm * 32 + rt * 16 + fc;
                const int seg = (kk * 4 + q) ^ (ar & 7);
                af[rt] = *(const f16x8*)((const char*)&As[cur][0] + ar * 128 + seg * 16);
            }
#pragma unroll
            for (int ct = 0; ct < 4; ++ct) {
                const f16x8 bf = *(const f16x8*)(&Bs[cur][wn * 64 + ct * 16 + fc][kk * 32 + q * 8]);
                acc[0][ct] = __builtin_amdgcn_mfma_f32_16x16x32_f16(af[0], bf, acc[0][ct], 0, 0, 0);
                acc[1][ct] = __builtin_amdgcn_mfma_f32_16x16x32_f16(af[1], bf, acc[1][ct], 0, 0, 0);
            }
        }

        if (p + 1 < NPH) {
            WRITE_B(p + 1, cur ^ 1, n0, n1, n2, n3)
            __syncthreads();
            cur ^= 1;
        }
    }
#undef ISSUE_A
#undef WRITE_B

    // flush h_sum partial (hsum_l complete: last atomics were before the last barrier)
    if (mtile == 0)
        atomicAdd(&ws[WS_HSUM + (ntile & (NSHARD - 1)) * H + tid], hsum_l[tid]);

    // ---- epilogue: sigmoid, * cs, reduce over 16 children per col-tile ----
    float* c_acc = ws + WS_CACC + (bid & (NSHARD - 1)) * H;
#pragma unroll
    for (int rt = 0; rt < 2; ++rt) {
        const int rglob = r0 + wm * 32 + rt * 16 + q * 4;
        float4 pf = *(const float4*)(pre_f + rglob);
        f32x4 csum = vzero;
#pragma unroll
        for (int ct = 0; ct < 4; ++ct) {
            const int child = c0 + wn * 64 + ct * 16 + fc;
            float4 cv = *(const float4*)(cs + (size_t)child * H + rglob);
            csum[0] += sigm(acc[rt][ct][0] + pf.x) * cv.x;
            csum[1] += sigm(acc[rt][ct][1] + pf.y) * cv.y;
            csum[2] += sigm(acc[rt][ct][2] + pf.z) * cv.z;
            csum[3] += sigm(acc[rt][ct][3] + pf.w) * cv.w;
        }
#pragma unroll
        for (int m = 1; m <= 8; m <<= 1) {
            csum[0] += __shfl_xor(csum[0], m); csum[1] += __shfl_xor(csum[1], m);
            csum[2] += __shfl_xor(csum[2], m); csum[3] += __shfl_xor(csum[3], m);
        }
        if (fc == 0) {
            atomicAdd(&c_acc[rglob + 0], csum[0]); atomicAdd(&c_acc[rglob + 1], csum[1]);
            atomicAdd(&c_acc[rglob + 2], csum[2]); atomicAdd(&c_acc[rglob + 3], csum[3]);
        }
    }
}

// k3: iou logits; reduces the 32 h_sum shards into LDS first. 96 blocks x 256 thr.
__global__ __launch_bounds__(256) void k3_iou(const float* __restrict__ x,
                                              const float* __restrict__ w_iou,
                                              const float* __restrict__ u_iou,
                                              const float* __restrict__ b_iou,
                                              float* __restrict__ ws) {
    __shared__ float h_red[H];
    const int tid = threadIdx.x;
    {
        float a0 = 0.0f, a1 = 0.0f;
#pragma unroll 8
        for (int s = 0; s < NSHARD; ++s) {
            a0 += ws[WS_HSUM + s * H + tid * 2 + 0];
            a1 += ws[WS_HSUM + s * H + tid * 2 + 1];
        }
        h_red[tid * 2 + 0] = a0;
        h_red[tid * 2 + 1] = a1;
    }
    __syncthreads();

    const int gid = blockIdx.x * 256 + tid;   // [0,24576)
    const int row = gid >> 4;                  // [0,1536)
    const int part = gid & 15;
    float acc = 0.0f;
    const float4* wr = (const float4*)(w_iou + (size_t)row * XD) + part * 4;
    const float4* xv = (const float4*)x + part * 4;
#pragma unroll
    for (int i = 0; i < 4; ++i) {
        float4 a = wr[i], b = xv[i];
        acc += a.x * b.x + a.y * b.y + a.z * b.z + a.w * b.w;
    }
    const float4* ur = (const float4*)(u_iou + (size_t)row * H) + part * 8;
    const float4* hv = (const float4*)h_red + part * 8;
#pragma unroll
    for (int i = 0; i < 8; ++i) {
        float4 a = ur[i], b = hv[i];
        acc += a.x * b.x + a.y * b.y + a.z * b.z + a.w * b.w;
    }
    acc += __shfl_xor(acc, 1);
    acc += __shfl_xor(acc, 2);
    acc += __shfl_xor(acc, 4);
    acc += __shfl_xor(acc, 8);
    if (part == 0) ws[WS_IOU + row] = acc + b_iou[row];
}

// k4: finalize c and h (sums the 32 c_acc shards).
__global__ __launch_bounds__(512) void k4_fin(const float* __restrict__ ws,
                                              float* __restrict__ out) {
    const int h = threadIdx.x;
    float cacc = 0.0f;
#pragma unroll 8
    for (int s = 0; s < NSHARD; ++s) cacc += ws[WS_CACC + s * H + h];
    const float i = sigm(ws[WS_IOU + h]);
    const float o = sigm(ws[WS_IOU + 512 + h]);
    const float u = tanhf(ws[WS_IOU + 1024 + h]);
    const float c = i * u + cacc;
    out[h]       = o * tanhf(c);
    out[512 + h] = c;
}

extern "C" void kernel_launch(void* const* d_in, const int* in_sizes, int n_in,
                              void* d_out, int out_size, void* d_ws, size_t ws_size,
                              hipStream_t stream) {
    const float* x     = (const float*)d_in[0];
    const float* hs    = (const float*)d_in[1];
    const float* cs    = (const float*)d_in[2];
    const float* w_iou = (const float*)d_in[3];
    const float* u_iou = (const float*)d_in[4];
    const float* b_iou = (const float*)d_in[5];
    const float* w_f   = (const float*)d_in[6];
    const float* u_f   = (const float*)d_in[7];
    const float* b_f   = (const float*)d_in[8];
    float* ws  = (float*)d_ws;
    float* out = (float*)d_out;

    k0_setup<<<264, 256, 0, stream>>>(x, w_f, b_f, u_f, ws);
    k2_main<<<(NCHLD / BN) * (H / BM), 512, 0, stream>>>(hs, cs, ws);
    k3_iou<<<96, 256, 0, stream>>>(x, w_iou, u_iou, b_iou, ws);
    k4_fin<<<1, 512, 0, stream>>>(ws, out);
}

// Round 6
// 220.901 us; speedup vs baseline: 1.1398x; 1.1398x over previous
//
#include <hip/hip_runtime.h>
#include <stdint.h>
#include <stddef.h>

#define H 512
#define XD 256
#define NCHLD 32768
#define NB 64               // children per k2 block
#define NSHARD 32

// ws layout (floats):
#define WS_PREF 0           // [0,512)       pre_f = w_f@x + b_f
#define WS_IOU  512         // [512,2048)    iou logits
#define WS_CACC 2048        // [2048,18432)  32 shards x 512
#define WS_HSUM 18432       // [18432,34816) 32 shards x 512
#define WS_UF16 34816       // u_f as f16: 262144 halves = 131072 float slots

typedef float f32x4 __attribute__((ext_vector_type(4)));
typedef _Float16 f16x8 __attribute__((ext_vector_type(8)));
typedef _Float16 f16x4 __attribute__((ext_vector_type(4)));

__device__ __forceinline__ float sigm(float x) { return 1.0f / (1.0f + __expf(-x)); }

// k0: (a) u_f -> f16 (blocks 0..255); (b) pre_f + zero shard arrays (blocks 256..263).
__global__ __launch_bounds__(256) void k0_setup(const float* __restrict__ x,
                                                const float* __restrict__ w_f,
                                                const float* __restrict__ b_f,
                                                const float* __restrict__ u_f,
                                                float* __restrict__ ws) {
    const int b = blockIdx.x;
    if (b < 256) {
        const int i = (b * 256 + threadIdx.x) * 4;
        float4 v = *(const float4*)(u_f + i);
        f16x4 h;
        h[0] = (_Float16)v.x; h[1] = (_Float16)v.y;
        h[2] = (_Float16)v.z; h[3] = (_Float16)v.w;
        *(f16x4*)((_Float16*)(ws + WS_UF16) + i) = h;
    } else {
        const int gid = (b - 256) * 256 + threadIdx.x;   // [0,2048)
        const int row = gid >> 2;
        const int part = gid & 3;
        const float4* wr = (const float4*)(w_f + (size_t)row * XD) + part * 16;
        const float4* xv = (const float4*)x + part * 16;
        float acc = 0.0f;
#pragma unroll 4
        for (int i = 0; i < 16; ++i) {
            float4 a = wr[i], c = xv[i];
            acc += a.x * c.x + a.y * c.y + a.z * c.z + a.w * c.w;
        }
        acc += __shfl_xor(acc, 1);
        acc += __shfl_xor(acc, 2);
        if (part == 0) ws[WS_PREF + row] = acc + b_f[row];
        // zero CACC+HSUM = floats [2048, 34816) = float4 idx [512, 8704)
        float4 z = make_float4(0.f, 0.f, 0.f, 0.f);
#pragma unroll
        for (int t = 0; t < 4; ++t)
            ((float4*)ws)[512 + gid * 4 + t] = z;
    }
}

// k1: h_sum = column-sum of hs. Pure streaming reduction: 512 blocks x 256 thr,
// 64 rows/block, thread owns a fixed 16B col-chunk -> 32 independent float4 loads.
__global__ __launch_bounds__(256) void k1_hsum(const float* __restrict__ hs,
                                               float* __restrict__ ws) {
    __shared__ float red[2][H];
    const int t = threadIdx.x;
    const int b = blockIdx.x;
    const float4* src = (const float4*)hs + (size_t)b * 64 * 128 + (t >> 7) * 128 + (t & 127);
    float4 a = make_float4(0.f, 0.f, 0.f, 0.f);
#pragma unroll
    for (int i = 0; i < 32; ++i) {             // rows b*64 + (t>>7) + 2i
        float4 v = src[(size_t)i * 256];
        a.x += v.x; a.y += v.y; a.z += v.z; a.w += v.w;
    }
    *(float4*)&red[t >> 7][(t & 127) * 4] = a;
    __syncthreads();
    float* shard = ws + WS_HSUM + (b & (NSHARD - 1)) * H;
    atomicAdd(&shard[t],       red[0][t]       + red[1][t]);
    atomicAdd(&shard[t + 256], red[0][t + 256] + red[1][t + 256]);
}

// k2: fs = sigmoid(pre_f + u_f@hs^T) fused with c partial-sums. BM=512 (all rows),
// NB=64 children/block, grid 512. B staged once to LDS f16 (XOR-swizzled, conflict-
// free), ONE barrier, fully-unrolled barrier-free K-loop (A streams from L2 uf16).
__global__ __launch_bounds__(512, 4) void k2_main(const float* __restrict__ hs,
                                                  const float* __restrict__ cs,
                                                  float* __restrict__ ws) {
    __shared__ _Float16 Bs[NB * H];   // 64 KB, swizzled: child*512 + ((g ^ (child&7))*8)

    const _Float16* uf16 = (const _Float16*)(ws + WS_UF16);
    const float* pre_f = ws + WS_PREF;
    float* c_acc = ws + WS_CACC + (blockIdx.x & (NSHARD - 1)) * H;

    const int tid  = threadIdx.x;
    const int wid  = tid >> 6;
    const int lane = tid & 63;
    const int c0   = blockIdx.x * NB;
    const int fc   = lane & 15;
    const int q    = lane >> 4;

    // ---- stage B: wave wid stages children {j*8+wid}, lane covers 32B of the row ----
    // global: hs[(c0+child)*512 + lane*8 .. +8] (f32, coalesced 2KB/wave)
    // LDS:    child*512 + ((lane ^ (child&7))*8)   [child&7 == wid, constant per wave]
    {
        const float4* g0 = (const float4*)hs + (((size_t)(c0 + wid)) << 7) + (lane << 1);
        _Float16* w0 = Bs + (wid << 9) + ((lane ^ wid) << 3);
        float4 r0[8], r1[8];
#pragma unroll
        for (int j = 0; j < 4; ++j) {
            r0[2 * j]     = g0[(size_t)j << 10];
            r0[2 * j + 1] = g0[((size_t)j << 10) + 1];
        }
#pragma unroll
        for (int j = 0; j < 4; ++j) {
            r1[2 * j]     = g0[(size_t)(j + 4) << 10];
            r1[2 * j + 1] = g0[((size_t)(j + 4) << 10) + 1];
        }
#pragma unroll
        for (int j = 0; j < 4; ++j) {
            f16x8 hv;
            hv[0] = (_Float16)r0[2*j].x;   hv[1] = (_Float16)r0[2*j].y;
            hv[2] = (_Float16)r0[2*j].z;   hv[3] = (_Float16)r0[2*j].w;
            hv[4] = (_Float16)r0[2*j+1].x; hv[5] = (_Float16)r0[2*j+1].y;
            hv[6] = (_Float16)r0[2*j+1].z; hv[7] = (_Float16)r0[2*j+1].w;
            *(f16x8*)(w0 + (j << 12)) = hv;
        }
#pragma unroll
        for (int j = 0; j < 4; ++j) {
            f16x8 hv;
            hv[0] = (_Float16)r1[2*j].x;   hv[1] = (_Float16)r1[2*j].y;
            hv[2] = (_Float16)r1[2*j].z;   hv[3] = (_Float16)r1[2*j].w;
            hv[4] = (_Float16)r1[2*j+1].x; hv[5] = (_Float16)r1[2*j+1].y;
            hv[6] = (_Float16)r1[2*j+1].z; hv[7] = (_Float16)r1[2*j+1].w;
            *(f16x8*)(w0 + ((j + 4) << 12)) = hv;
        }
    }
    __syncthreads();   // the ONLY barrier

    // ---- barrier-free K-loop: wave owns rows [wid*64, wid*64+64) ----
    f32x4 acc[4][4];
    const f32x4 vzero = {0.0f, 0.0f, 0.0f, 0.0f};
#pragma unroll
    for (int rt = 0; rt < 4; ++rt)
#pragma unroll
        for (int ct = 0; ct < 4; ++ct)
            acc[rt][ct] = vzero;

    const _Float16* abase = uf16 + (size_t)(wid * 64 + fc) * H + q * 8;

#pragma unroll
    for (int kk = 0; kk < 16; ++kk) {
        f16x8 af[4];
#pragma unroll
        for (int rt = 0; rt < 4; ++rt)
            af[rt] = *(const f16x8*)(abase + (size_t)rt * 16 * H + kk * 32);
        f16x8 bf[4];
#pragma unroll
        for (int ct = 0; ct < 4; ++ct) {
            const int ch = ct * 16 + fc;
            bf[ct] = *(const f16x8*)(Bs + ch * H + (((kk * 4 + q) ^ (fc & 7)) << 3));
        }
#pragma unroll
        for (int ct = 0; ct < 4; ++ct)
#pragma unroll
            for (int rt = 0; rt < 4; ++rt)
                acc[rt][ct] = __builtin_amdgcn_mfma_f32_16x16x32_f16(af[rt], bf[ct], acc[rt][ct], 0, 0, 0);
    }

    // ---- epilogue: sigmoid, * cs, reduce over 16 children per col-tile ----
#pragma unroll
    for (int rt = 0; rt < 4; ++rt) {
        const int rglob = wid * 64 + rt * 16 + q * 4;
        float4 pf = *(const float4*)(pre_f + rglob);
        f32x4 csum = vzero;
#pragma unroll
        for (int ct = 0; ct < 4; ++ct) {
            const int child = c0 + ct * 16 + fc;
            float4 cv = *(const float4*)(cs + (size_t)child * H + rglob);
            csum[0] += sigm(acc[rt][ct][0] + pf.x) * cv.x;
            csum[1] += sigm(acc[rt][ct][1] + pf.y) * cv.y;
            csum[2] += sigm(acc[rt][ct][2] + pf.z) * cv.z;
            csum[3] += sigm(acc[rt][ct][3] + pf.w) * cv.w;
        }
#pragma unroll
        for (int m = 1; m <= 8; m <<= 1) {
            csum[0] += __shfl_xor(csum[0], m); csum[1] += __shfl_xor(csum[1], m);
            csum[2] += __shfl_xor(csum[2], m); csum[3] += __shfl_xor(csum[3], m);
        }
        if (fc == 0) {
            atomicAdd(&c_acc[rglob + 0], csum[0]); atomicAdd(&c_acc[rglob + 1], csum[1]);
            atomicAdd(&c_acc[rglob + 2], csum[2]); atomicAdd(&c_acc[rglob + 3], csum[3]);
        }
    }
}

// k3: iou logits; reduces the 32 h_sum shards into LDS first. 96 blocks x 256 thr.
__global__ __launch_bounds__(256) void k3_iou(const float* __restrict__ x,
                                              const float* __restrict__ w_iou,
                                              const float* __restrict__ u_iou,
                                              const float* __restrict__ b_iou,
                                              float* __restrict__ ws) {
    __shared__ float h_red[H];
    const int tid = threadIdx.x;
    {
        float a0 = 0.0f, a1 = 0.0f;
#pragma unroll 8
        for (int s = 0; s < NSHARD; ++s) {
            a0 += ws[WS_HSUM + s * H + tid * 2 + 0];
            a1 += ws[WS_HSUM + s * H + tid * 2 + 1];
        }
        h_red[tid * 2 + 0] = a0;
        h_red[tid * 2 + 1] = a1;
    }
    __syncthreads();

    const int gid = blockIdx.x * 256 + tid;   // [0,24576)
    const int row = gid >> 4;                  // [0,1536)
    const int part = gid & 15;
    float acc = 0.0f;
    const float4* wr = (const float4*)(w_iou + (size_t)row * XD) + part * 4;
    const float4* xv = (const float4*)x + part * 4;
#pragma unroll
    for (int i = 0; i < 4; ++i) {
        float4 a = wr[i], b = xv[i];
        acc += a.x * b.x + a.y * b.y + a.z * b.z + a.w * b.w;
    }
    const float4* ur = (const float4*)(u_iou + (size_t)row * H) + part * 8;
    const float4* hv = (const float4*)h_red + part * 8;
#pragma unroll
    for (int i = 0; i < 8; ++i) {
        float4 a = ur[i], b = hv[i];
        acc += a.x * b.x + a.y * b.y + a.z * b.z + a.w * b.w;
    }
    acc += __shfl_xor(acc, 1);
    acc += __shfl_xor(acc, 2);
    acc += __shfl_xor(acc, 4);
    acc += __shfl_xor(acc, 8);
    if (part == 0) ws[WS_IOU + row] = acc + b_iou[row];
}

// k4: finalize c and h (sums the 32 c_acc shards).
__global__ __launch_bounds__(512) void k4_fin(const float* __restrict__ ws,
                                              float* __restrict__ out) {
    const int h = threadIdx.x;
    float cacc = 0.0f;
#pragma unroll 8
    for (int s = 0; s < NSHARD; ++s) cacc += ws[WS_CACC + s * H + h];
    const float i = sigm(ws[WS_IOU + h]);
    const float o = sigm(ws[WS_IOU + 512 + h]);
    const float u = tanhf(ws[WS_IOU + 1024 + h]);
    const float c = i * u + cacc;
    out[h]       = o * tanhf(c);
    out[512 + h] = c;
}

extern "C" void kernel_launch(void* const* d_in, const int* in_sizes, int n_in,
                              void* d_out, int out_size, void* d_ws, size_t ws_size,
                              hipStream_t stream) {
    const float* x     = (const float*)d_in[0];
    const float* hs    = (const float*)d_in[1];
    const float* cs    = (const float*)d_in[2];
    const float* w_iou = (const float*)d_in[3];
    const float* u_iou = (const float*)d_in[4];
    const float* b_iou = (const float*)d_in[5];
    const float* w_f   = (const float*)d_in[6];
    const float* u_f   = (const float*)d_in[7];
    const float* b_f   = (const float*)d_in[8];
    float* ws  = (float*)d_ws;
    float* out = (float*)d_out;

    k0_setup<<<264, 256, 0, stream>>>(x, w_f, b_f, u_f, ws);
    k1_hsum<<<512, 256, 0, stream>>>(hs, ws);
    k2_main<<<NCHLD / NB, 512, 0, stream>>>(hs, cs, ws);
    k3_iou<<<96, 256, 0, stream>>>(x, w_iou, u_iou, b_iou, ws);
    k4_fin<<<1, 512, 0, stream>>>(ws, out);
}

// Round 7
// 215.388 us; speedup vs baseline: 1.1690x; 1.0256x over previous
//
#include <hip/hip_runtime.h>
#include <stdint.h>
#include <stddef.h>

#define H 512
#define XD 256
#define NCHLD 32768
#define NB 64               // children per k2 block
#define NSHARD 32

// ws layout (floats):
#define WS_PREF 0           // [0,512)       pre_f = w_f@x + b_f
#define WS_IOU  512         // [512,2048)    iou logits
#define WS_CACC 2048        // [2048,18432)  32 shards x 512
#define WS_HSUM 18432       // [18432,34816) 32 shards x 512
#define WS_UF16 34816       // u_f as f16: 262144 halves = 131072 float slots

typedef float f32x4 __attribute__((ext_vector_type(4)));
typedef _Float16 f16x8 __attribute__((ext_vector_type(8)));
typedef _Float16 f16x4 __attribute__((ext_vector_type(4)));

__device__ __forceinline__ float sigm(float x) { return 1.0f / (1.0f + __expf(-x)); }

// k0: (a) u_f -> f16 (blocks 0..255); (b) pre_f + zero shard arrays (blocks 256..263).
__global__ __launch_bounds__(256) void k0_setup(const float* __restrict__ x,
                                                const float* __restrict__ w_f,
                                                const float* __restrict__ b_f,
                                                const float* __restrict__ u_f,
                                                float* __restrict__ ws) {
    const int b = blockIdx.x;
    if (b < 256) {
        const int i = (b * 256 + threadIdx.x) * 4;
        float4 v = *(const float4*)(u_f + i);
        f16x4 h;
        h[0] = (_Float16)v.x; h[1] = (_Float16)v.y;
        h[2] = (_Float16)v.z; h[3] = (_Float16)v.w;
        *(f16x4*)((_Float16*)(ws + WS_UF16) + i) = h;
    } else {
        const int gid = (b - 256) * 256 + threadIdx.x;   // [0,2048)
        const int row = gid >> 2;
        const int part = gid & 3;
        const float4* wr = (const float4*)(w_f + (size_t)row * XD) + part * 16;
        const float4* xv = (const float4*)x + part * 16;
        float acc = 0.0f;
#pragma unroll 4
        for (int i = 0; i < 16; ++i) {
            float4 a = wr[i], c = xv[i];
            acc += a.x * c.x + a.y * c.y + a.z * c.z + a.w * c.w;
        }
        acc += __shfl_xor(acc, 1);
        acc += __shfl_xor(acc, 2);
        if (part == 0) ws[WS_PREF + row] = acc + b_f[row];
        // zero CACC+HSUM = floats [2048, 34816) = float4 idx [512, 8704)
        float4 z = make_float4(0.f, 0.f, 0.f, 0.f);
#pragma unroll
        for (int t = 0; t < 4; ++t)
            ((float4*)ws)[512 + gid * 4 + t] = z;
    }
}

// k2: fs = sigmoid(pre_f + u_f@hs^T) fused with c partial-sums AND h_sum partials.
// BM=512 (all rows), NB=64 children/block, grid 512. B staged once to LDS f16
// (XOR-swizzled), 2 barriers total, barrier-free fully-unrolled K-loop.
// launch_bounds(512,2): allow ~256 regs -> deep load pipelining, 1 block/CU.
__global__ __launch_bounds__(512, 2) void k2_main(const float* __restrict__ hs,
                                                  const float* __restrict__ cs,
                                                  float* __restrict__ ws) {
    __shared__ _Float16 Bs[NB * H];   // 64 KB, swizzled: child*512 + ((g ^ (child&7))*8)
    __shared__ float hsum_l[H];       // 2 KB

    const _Float16* uf16 = (const _Float16*)(ws + WS_UF16);
    const float* pre_f = ws + WS_PREF;
    float* c_acc   = ws + WS_CACC + (blockIdx.x & (NSHARD - 1)) * H;
    float* h_shard = ws + WS_HSUM + (blockIdx.x & (NSHARD - 1)) * H;

    const int tid  = threadIdx.x;
    const int wid  = tid >> 6;
    const int lane = tid & 63;
    const int c0   = blockIdx.x * NB;
    const int fc   = lane & 15;
    const int q    = lane >> 4;

    hsum_l[tid] = 0.0f;
    __syncthreads();    // barrier 1 (nothing in flight, cheap)

    // ---- stage B + h_sum: wave wid owns children {8j+wid}, lane owns dims [lane*8,+8) ----
    {
        const float4* g0 = (const float4*)hs + (((size_t)(c0 + wid)) << 7) + (lane << 1);
        _Float16* w0 = Bs + (wid << 9) + ((lane ^ wid) << 3);
        float4 r[16];
#pragma unroll
        for (int j = 0; j < 8; ++j) {        // issue all 16 loads up front
            r[2 * j]     = g0[(size_t)j << 10];
            r[2 * j + 1] = g0[((size_t)j << 10) + 1];
        }
        float4 ha = make_float4(0.f, 0.f, 0.f, 0.f);
        float4 hb = make_float4(0.f, 0.f, 0.f, 0.f);
#pragma unroll
        for (int j = 0; j < 8; ++j) {
            float4 lo = r[2 * j], hi = r[2 * j + 1];
            f16x8 hv;
            hv[0] = (_Float16)lo.x; hv[1] = (_Float16)lo.y;
            hv[2] = (_Float16)lo.z; hv[3] = (_Float16)lo.w;
            hv[4] = (_Float16)hi.x; hv[5] = (_Float16)hi.y;
            hv[6] = (_Float16)hi.z; hv[7] = (_Float16)hi.w;
            *(f16x8*)(w0 + (j << 12)) = hv;
            ha.x += lo.x; ha.y += lo.y; ha.z += lo.z; ha.w += lo.w;
            hb.x += hi.x; hb.y += hi.y; hb.z += hi.z; hb.w += hi.w;
        }
        // per-lane partial (8 children) -> LDS atomic (hidden under load latency)
        float* hd = &hsum_l[lane * 8];
        atomicAdd(hd + 0, ha.x); atomicAdd(hd + 1, ha.y);
        atomicAdd(hd + 2, ha.z); atomicAdd(hd + 3, ha.w);
        atomicAdd(hd + 4, hb.x); atomicAdd(hd + 5, hb.y);
        atomicAdd(hd + 6, hb.z); atomicAdd(hd + 7, hb.w);
    }
    __syncthreads();    // barrier 2: tile + hsum_l complete

    // flush block-partial h_sum (independent, overlaps with what follows)
    atomicAdd(&h_shard[tid], hsum_l[tid]);

    // ---- prefetch cs for the epilogue: latency hides under the K-loop ----
    float4 csr[4][4];
#pragma unroll
    for (int rt = 0; rt < 4; ++rt)
#pragma unroll
        for (int ct = 0; ct < 4; ++ct) {
            const int child = c0 + ct * 16 + fc;
            const int rglob = wid * 64 + rt * 16 + q * 4;
            csr[rt][ct] = *(const float4*)(cs + (size_t)child * H + rglob);
        }

    // ---- barrier-free K-loop: wave owns rows [wid*64, wid*64+64) ----
    f32x4 acc[4][4];
    const f32x4 vzero = {0.0f, 0.0f, 0.0f, 0.0f};
#pragma unroll
    for (int rt = 0; rt < 4; ++rt)
#pragma unroll
        for (int ct = 0; ct < 4; ++ct)
            acc[rt][ct] = vzero;

    const _Float16* abase = uf16 + (size_t)(wid * 64 + fc) * H + q * 8;

#pragma unroll
    for (int kk = 0; kk < 16; ++kk) {
        f16x8 af[4];
#pragma unroll
        for (int rt = 0; rt < 4; ++rt)
            af[rt] = *(const f16x8*)(abase + (size_t)rt * 16 * H + kk * 32);
        f16x8 bf[4];
#pragma unroll
        for (int ct = 0; ct < 4; ++ct) {
            const int ch = ct * 16 + fc;
            bf[ct] = *(const f16x8*)(Bs + ch * H + (((kk * 4 + q) ^ (fc & 7)) << 3));
        }
#pragma unroll
        for (int ct = 0; ct < 4; ++ct)
#pragma unroll
            for (int rt = 0; rt < 4; ++rt)
                acc[rt][ct] = __builtin_amdgcn_mfma_f32_16x16x32_f16(af[rt], bf[ct], acc[rt][ct], 0, 0, 0);
    }

    // ---- epilogue: sigmoid, * cs (prefetched), reduce over 16 children per col-tile ----
#pragma unroll
    for (int rt = 0; rt < 4; ++rt) {
        const int rglob = wid * 64 + rt * 16 + q * 4;
        float4 pf = *(const float4*)(pre_f + rglob);
        f32x4 csum = vzero;
#pragma unroll
        for (int ct = 0; ct < 4; ++ct) {
            float4 cv = csr[rt][ct];
            csum[0] += sigm(acc[rt][ct][0] + pf.x) * cv.x;
            csum[1] += sigm(acc[rt][ct][1] + pf.y) * cv.y;
            csum[2] += sigm(acc[rt][ct][2] + pf.z) * cv.z;
            csum[3] += sigm(acc[rt][ct][3] + pf.w) * cv.w;
        }
#pragma unroll
        for (int m = 1; m <= 8; m <<= 1) {
            csum[0] += __shfl_xor(csum[0], m); csum[1] += __shfl_xor(csum[1], m);
            csum[2] += __shfl_xor(csum[2], m); csum[3] += __shfl_xor(csum[3], m);
        }
        if (fc == 0) {
            atomicAdd(&c_acc[rglob + 0], csum[0]); atomicAdd(&c_acc[rglob + 1], csum[1]);
            atomicAdd(&c_acc[rglob + 2], csum[2]); atomicAdd(&c_acc[rglob + 3], csum[3]);
        }
    }
}

// k3: iou logits; reduces the 32 h_sum shards into LDS first. 96 blocks x 256 thr.
__global__ __launch_bounds__(256) void k3_iou(const float* __restrict__ x,
                                              const float* __restrict__ w_iou,
                                              const float* __restrict__ u_iou,
                                              const float* __restrict__ b_iou,
                                              float* __restrict__ ws) {
    __shared__ float h_red[H];
    const int tid = threadIdx.x;
    {
        float a0 = 0.0f, a1 = 0.0f;
#pragma unroll 8
        for (int s = 0; s < NSHARD; ++s) {
            a0 += ws[WS_HSUM + s * H + tid * 2 + 0];
            a1 += ws[WS_HSUM + s * H + tid * 2 + 1];
        }
        h_red[tid * 2 + 0] = a0;
        h_red[tid * 2 + 1] = a1;
    }
    __syncthreads();

    const int gid = blockIdx.x * 256 + tid;   // [0,24576)
    const int row = gid >> 4;                  // [0,1536)
    const int part = gid & 15;
    float acc = 0.0f;
    const float4* wr = (const float4*)(w_iou + (size_t)row * XD) + part * 4;
    const float4* xv = (const float4*)x + part * 4;
#pragma unroll
    for (int i = 0; i < 4; ++i) {
        float4 a = wr[i], b = xv[i];
        acc += a.x * b.x + a.y * b.y + a.z * b.z + a.w * b.w;
    }
    const float4* ur = (const float4*)(u_iou + (size_t)row * H) + part * 8;
    const float4* hv = (const float4*)h_red + part * 8;
#pragma unroll
    for (int i = 0; i < 8; ++i) {
        float4 a = ur[i], b = hv[i];
        acc += a.x * b.x + a.y * b.y + a.z * b.z + a.w * b.w;
    }
    acc += __shfl_xor(acc, 1);
    acc += __shfl_xor(acc, 2);
    acc += __shfl_xor(acc, 4);
    acc += __shfl_xor(acc, 8);
    if (part == 0) ws[WS_IOU + row] = acc + b_iou[row];
}

// k4: finalize c and h (sums the 32 c_acc shards).
__global__ __launch_bounds__(512) void k4_fin(const float* __restrict__ ws,
                                              float* __restrict__ out) {
    const int h = threadIdx.x;
    float cacc = 0.0f;
#pragma unroll 8
    for (int s = 0; s < NSHARD; ++s) cacc += ws[WS_CACC + s * H + h];
    const float i = sigm(ws[WS_IOU + h]);
    const float o = sigm(ws[WS_IOU + 512 + h]);
    const float u = tanhf(ws[WS_IOU + 1024 + h]);
    const float c = i * u + cacc;
    out[h]       = o * tanhf(c);
    out[512 + h] = c;
}

extern "C" void kernel_launch(void* const* d_in, const int* in_sizes, int n_in,
                              void* d_out, int out_size, void* d_ws, size_t ws_size,
                              hipStream_t stream) {
    const float* x     = (const float*)d_in[0];
    const float* hs    = (const float*)d_in[1];
    const float* cs    = (const float*)d_in[2];
    const float* w_iou = (const float*)d_in[3];
    const float* u_iou = (const float*)d_in[4];
    const float* b_iou = (const float*)d_in[5];
    const float* w_f   = (const float*)d_in[6];
    const float* u_f   = (const float*)d_in[7];
    const float* b_f   = (const float*)d_in[8];
    float* ws  = (float*)d_ws;
    float* out = (float*)d_out;

    k0_setup<<<264, 256, 0, stream>>>(x, w_f, b_f, u_f, ws);
    k2_main<<<NCHLD / NB, 512, 0, stream>>>(hs, cs, ws);
    k3_iou<<<96, 256, 0, stream>>>(x, w_iou, u_iou, b_iou, ws);
    k4_fin<<<1, 512, 0, stream>>>(ws, out);
}